// Round 4
// baseline (224.396 us; speedup 1.0000x reference)
//
#include <hip/hip_runtime.h>

// CTC forward loss, B=256, T=1024, C=128, L=64, S=2L+1=129, BLANK=127.
// One wave per batch element (256 blocks x 64 threads).
//
// Round 12: I-FETCH hypothesis. Evidence so far:
//   R8  (2 ds_read/step, full unroll)          210.6us  absmax 0
//   R10 (zero mem ops in body, full unroll)    206.9us  absmax 0
//   R11 (chain 8->5 deps, full unroll)         196.7us  absmax 96 (REVERTED:
//        uniform-exponent flushes lanes whose future path products dominate;
//        per-lane exponents are load-bearing)
// Neither memory path nor chain length moves the ~190-200ns/step floor, but
// every variant streamed ~120-160KB of fully-unrolled code through a 32KB
// L1I with zero reuse -> instruction fetch misses pin the step cost.
// This round: IDENTICAL R8 math (verified absmax 0.0), but rolled loops:
// outer chunk loop (31x) + inner group loop (7x, 4 steps unrolled so the
// 4-deep ring has compile-time indices) + one peeled boundary group.
// Hot code ~2KB -> I$-resident after the first chunk.
// Memory path: 3-slot LDS rotation (48KB), global_load_lds w16 staging of
// chunk c+2 during chunk c, ONE vmcnt(0) per 32 steps.

#define B_     256
#define T_     1024
#define C_     128
#define L_     64
#define BLANK_ 127
#define EPS_   1e-7f
#define LN2_   0.69314718055994530942f
#define ROWS   32
#define LDSF   (ROWS * C_)      // 4096 floats = 16 KB per slot

__device__ __forceinline__ float flog2(float x) { return __builtin_amdgcn_logf(x); }

template <int CTRL>
__device__ __forceinline__ int dpp_i(int x) {
    return __builtin_amdgcn_update_dpp(x, x, CTRL, 0xF, 0xF, false);
}
// whole-wave rotate: lane i receives lane (i-1)&63
__device__ __forceinline__ float ror1_f(float x) {
    return __int_as_float(dpp_i<0x13C>(__float_as_int(x)));
}
__device__ __forceinline__ int ror1_i(int x) { return dpp_i<0x13C>(x); }

__device__ __forceinline__ float fldexp(float x, int n) {
#if __has_builtin(__builtin_amdgcn_ldexpf)
    return __builtin_amdgcn_ldexpf(x, n);
#else
    return ldexpf(x, n);
#endif
}
// frexp-style exponent; 0 for x==0
__device__ __forceinline__ int fexp_of(float x) {
#if __has_builtin(__builtin_amdgcn_frexp_expf)
    return __builtin_amdgcn_frexp_expf(x);
#else
    const int bx = (__float_as_int(x) >> 23) & 0xFF;
    return (x > 0.0f) ? (bx - 126) : 0;
#endif
}

// global -> LDS direct copy, 16 B/lane (1 KB/instr). LDS dest is the
// wave-uniform base; HW lands lane i at base + i*16.
typedef const __attribute__((address_space(1))) void gas_void;
typedef __attribute__((address_space(3))) void las_void;
__device__ __forceinline__ void g2l16(const float* g, float* l) {
    __builtin_amdgcn_global_load_lds((gas_void*)g, (las_void*)l, 16, 0, 0);
}
__device__ __forceinline__ void g2l4(const float* g, float* l) {
    __builtin_amdgcn_global_load_lds((gas_void*)g, (las_void*)l, 4, 0, 0);
}

// One DP step (verified math, rounds 6/7/8/10: absmax 0.0): linear recursion
// on f32 mantissas with per-lane int exponent e; dead lanes adopt the
// neighbor's exponent so the DP front is never flushed; ldexp(0,n)=0 keeps
// lane-0 wraparound garbage out of live arithmetic.
#define LSTEP(pL, pB)                                                         \
    {                                                                         \
        const float pBe = (pB) + EPS_;                                        \
        const float pLe = (pL) + EPS_;                                        \
        const int   ep  = ror1_i(e);                                          \
        const float mpE = ror1_f(aE);                                         \
        const float mpO = ror1_f(aO);                                         \
        const bool dead = (fmaxf(aE, aO) == 0.0f);                            \
        e = dead ? ep : e;                                                    \
        const int   d   = ep - e;                                             \
        float prevE = fldexp(mpE, d);                                         \
        const float prevO = fldexp(mpO, d);                                   \
        prevE = isL0 ? fldexp(a0, e0 - e) : prevE;                            \
        const float sk = can_skip ? prevO : 0.0f;                             \
        const float nE = (aE + aO) * pBe;                                     \
        const float nO = (aO + prevE + sk) * pLe;                             \
        a0 *= pBe;                                                            \
        aE = nE; aO = nO;                                                     \
    }

// Renorm every 4 steps (shrink >= pmin^4 = 2^-68: no underflow; growth <=
// 6^4: no overflow). frexp_exp(0)=0 so dead lanes are a no-op.
#define RENORM4                                                               \
    {                                                                         \
        const int x = fexp_of(fmaxf(aE, aO));                                 \
        aE = fldexp(aE, -x); aO = fldexp(aO, -x); e += x;                     \
        const int x0 = fexp_of(a0);                                           \
        a0 = fldexp(a0, -x0); e0 += x0;                                       \
    }

// Stage chunk k (rows t = 1+32k .. 32+32k; k==31 -> final 31 rows) into
// LDS at float offset LOFF. Rolled (code size); k runtime, wave-uniform.
#define STAGE_CHUNK(k, LOFF)                                                  \
    {                                                                         \
        const float* src = base + (size_t)(1 + 32 * (k)) * C_;                \
        const int nKB = ((k) == 31) ? 15 : 16;                                \
        _Pragma("unroll 1")                                                   \
        for (int j = 0; j < nKB; ++j)                                         \
            g2l16(src + j * 256 + lane * 4, sm + (LOFF) + j * 256);           \
        if ((k) == 31) {                                                      \
            const float* s2 = src + 15 * 256;                                 \
            g2l4(s2 + lane,      sm + (LOFF) + 15 * 256);                     \
            g2l4(s2 + 64 + lane, sm + (LOFF) + 15 * 256 + 64);                \
        }                                                                     \
    }

#define VMWAIT asm volatile("s_waitcnt vmcnt(0)" ::: "memory")

__global__ __launch_bounds__(64, 1)
void ctc_fwd(const int* __restrict__ yt, const float* __restrict__ yp,
             float* __restrict__ out) {
    __shared__ float sm[3 * LDSF];                // 48 KB, 3-slot rotation

    const int b    = blockIdx.x;
    const int lane = threadIdx.x;                 // 0..63
    const int lab  = yt[b * L_ + lane];           // label of state 2*lane+1
    const int labp = __shfl_up(lab, 1);           // init-only, off hot path
    const bool can_skip = (lane > 0) && (lab != labp);
    const bool isL0     = (lane == 0);

    const float* __restrict__ base = yp + (size_t)b * T_ * C_;

    // ---- prologue: stage chunks 0 and 1 (rows 1..64) ----
    STAGE_CHUNK(0, 0)
    STAGE_CHUNK(1, LDSF)

    // ---- t=0 init (linear, exponent 0): only states 0 and 1 reachable ----
    float a0 = base[BLANK_] + EPS_;               // state 0 (uniform)
    float aO = isL0 ? (base[lab] + EPS_) : 0.0f;  // state 2i+1
    float aE = 0.0f;                              // state 2i+2
    int   e  = 0, e0 = 0;

    VMWAIT;                                       // slots 0,1 + init loads

    // ---- 4-deep ring: rows 0..3 of chunk 0 (t = 1..4) ----
    float rL[4], rB[4];
#pragma unroll
    for (int j = 0; j < 4; ++j) {
        rL[j] = sm[j * C_ + lab];
        rB[j] = sm[j * C_ + BLANK_];
    }

    // ---- chunks 0..30 (32 steps each; t = 1..992) ----
#pragma unroll 1
    for (int c = 0; c < 31; ++c) {
        const int bc = (c % 3) * LDSF;            // current slot
        const int bn = ((c + 1) % 3) * LDSF;      // next slot
        if (c <= 29)                              // stage chunk c+2
            STAGE_CHUNK(c + 2, ((c + 2) % 3) * LDSF)
        // groups 0..6: steps 4g..4g+3 consume ring, prefetch rows 4g+4..4g+7
        const float* pf = &sm[bc + 4 * C_];
#pragma unroll 1
        for (int g = 0; g < 7; ++g) {
#pragma unroll
            for (int j = 0; j < 4; ++j) {
                const float pL = rL[j];
                const float pB = rB[j];
                rL[j] = pf[lab];
                rB[j] = pf[BLANK_];
                pf += C_;
                LSTEP(pL, pB)
            }
            RENORM4
        }
        // peeled group 7: steps 28..31, prefetch rows 0..3 of next chunk
        {
            const float* pn = &sm[bn];
#pragma unroll
            for (int j = 0; j < 4; ++j) {
                const float pL = rL[j];
                const float pB = rB[j];
                rL[j] = pn[lab];
                rB[j] = pn[BLANK_];
                pn += C_;
                LSTEP(pL, pB)
            }
            RENORM4
        }
        VMWAIT;                                   // stage c+2 landed
    }

    // ---- final chunk 31: t = 993..1023 (31 steps), slot 31%3 = 1 ----
    {
        const int bc = (31 % 3) * LDSF;
        const float* pf = &sm[bc + 4 * C_];
#pragma unroll 1
        for (int g = 0; g < 7; ++g) {             // steps 0..27
#pragma unroll
            for (int j = 0; j < 4; ++j) {
                const float pL = rL[j];
                const float pB = rB[j];
                rL[j] = pf[lab];                  // g=6,j=3 reads stale row 31:
                rB[j] = pf[BLANK_];               //   value never consumed
                pf += C_;
                LSTEP(pL, pB)
            }
            RENORM4
        }
#pragma unroll
        for (int j = 0; j < 3; ++j) {             // steps 28..30
            const float pL = rL[j];
            const float pB = rB[j];
            LSTEP(pL, pB)
        }
    }

    // loss = -ln(alpha[127] + alpha[128]); both live in lane 63 at scale 2^e.
    if (lane == 63) {
        const float s = aE + aO;                  // in [2^-70, 8): v_log safe
        out[b] = -(flog2(s) + (float)e) * LN2_;
    }
}

extern "C" void kernel_launch(void* const* d_in, const int* in_sizes, int n_in,
                              void* d_out, int out_size, void* d_ws, size_t ws_size,
                              hipStream_t stream) {
    const int*   y_true = (const int*)d_in[0];
    const float* y_pred = (const float*)d_in[1];
    float*       out    = (float*)d_out;
    ctc_fwd<<<B_, 64, 0, stream>>>(y_true, y_pred, out);
}

// Round 6
// 198.148 us; speedup vs baseline: 1.1325x; 1.1325x over previous
//
#include <hip/hip_runtime.h>

// CTC forward loss, B=256, T=1024, C=128, L=64, S=2L+1=129, BLANK=127.
// One wave per batch element (256 blocks x 64 threads).
//
// Round 14. Model from counters (R12: VALUBusy 14%, HBM 9.6%, 86% stall;
// R8/R10/R11/R12 all fit time ~ N_instr x ~7-9cyc): solo-wave issue/latency
// cadence -> minimize instructions per step.
//
// R13 inf ROOT CAUSE: "all lanes live after t=64" is FALSE when labels
// repeat (skips blocked; worst case front reaches state 127 at t=126).
// Phase B had no dead-lane adoption -> dead lane's e froze -> inflows
// flushed forever -> s=0 -> -log(0)=inf. Fix: phase A (with per-step
// adoption) covers t=1..128 >= worst-case front arrival for ANY labels.
//
// This round:
//  - STATE REMAP: lane i holds states (2i, 2i+1)  [was (2i+1, 2i+2)].
//    * O's blank predecessor (state 2i) is SAME-LANE aE -> only ONE
//      cross-lane value per step (O of lane i-1), feeding nE and skip.
//    * state 0 IS lane 0's aE -> a0/e0 side-channel deleted.
//    * state 128 = scalar aZ on lane 63: same-lane recursion (add+mul).
//  - Phase A (t=1..128): remapped step WITH per-step adoption (4 chunks).
//  - Phase B (t=129..1023): lean 11-instr step; alignment delta d frozen
//    between renorms (recomputed per 4-step boundary); lane-0 masked via
//    d=-16384 (ldexp underflows to 0 -> no cndmask).
// Memory path (verified R10/R12): 3-slot LDS rotation, global_load_lds w16,
// full-chunk register operand bursts, ONE vmcnt(0) per 32 steps.

#define B_     256
#define T_     1024
#define C_     128
#define L_     64
#define BLANK_ 127
#define EPS_   1e-7f
#define LN2_   0.69314718055994530942f
#define ROWS   32
#define LDSF   (ROWS * C_)      // 4096 floats = 16 KB per slot

__device__ __forceinline__ float flog2(float x) { return __builtin_amdgcn_logf(x); }

template <int CTRL>
__device__ __forceinline__ int dpp_i(int x) {
    return __builtin_amdgcn_update_dpp(x, x, CTRL, 0xF, 0xF, false);
}
// whole-wave rotate: lane i receives lane (i-1)&63
__device__ __forceinline__ float ror1_f(float x) {
    return __int_as_float(dpp_i<0x13C>(__float_as_int(x)));
}
__device__ __forceinline__ int ror1_i(int x) { return dpp_i<0x13C>(x); }

__device__ __forceinline__ float fldexp(float x, int n) {
#if __has_builtin(__builtin_amdgcn_ldexpf)
    return __builtin_amdgcn_ldexpf(x, n);
#else
    return ldexpf(x, n);
#endif
}
// frexp-style exponent; 0 for x==0
__device__ __forceinline__ int fexp_of(float x) {
#if __has_builtin(__builtin_amdgcn_frexp_expf)
    return __builtin_amdgcn_frexp_expf(x);
#else
    const int bx = (__float_as_int(x) >> 23) & 0xFF;
    return (x > 0.0f) ? (bx - 126) : 0;
#endif
}

// global -> LDS direct copy, 16 B/lane (1 KB/instr).
typedef const __attribute__((address_space(1))) void gas_void;
typedef __attribute__((address_space(3))) void las_void;
__device__ __forceinline__ void g2l16(const float* g, float* l) {
    __builtin_amdgcn_global_load_lds((gas_void*)g, (las_void*)l, 16, 0, 0);
}
__device__ __forceinline__ void g2l4(const float* g, float* l) {
    __builtin_amdgcn_global_load_lds((gas_void*)g, (las_void*)l, 4, 0, 0);
}

// ---- phase-A step: remapped, per-step dead-lane adoption ----
// Recursions (lane i; E=state 2i, O=state 2i+1, prevO=state 2i-1):
//   nE = (aE + prevO)        * pB     (blank: no skip)
//   nO = (aO + aE + sk*prevO)* pL
//   aZ = (aZ + aO)           * pB     (state 128; valid on lane 63)
// Dead lane (aE=aO=0) adopts neighbor exponent -> dd=0 -> front lands exact.
#define ALSTEP(pL, pB)                                                        \
    {                                                                         \
        const float pBe = (pB) + EPS_;                                        \
        const float pLe = (pL) + EPS_;                                        \
        const int   ep  = ror1_i(e);                                          \
        const float mpO = ror1_f(aO);                                         \
        const bool dead = (fmaxf(aE, aO) == 0.0f);                            \
        e = dead ? ep : e;                                                    \
        const int   dd  = ep - e;                                             \
        float prevO = fldexp(mpO, dd);                                        \
        prevO = isL0 ? 0.0f : prevO;                                          \
        const float sk = can_skip ? prevO : 0.0f;                             \
        const float nE = (aE + prevO) * pBe;                                  \
        const float nO = (aO + aE + sk) * pLe;                                \
        aZ = (aZ + aO) * pBe;                                                 \
        aE = nE; aO = nO;                                                     \
    }

// Renorm every 4 steps (shrink >= (1e-7)^4 ~= 2^-93 from [0.5,1): no flush;
// growth bounded by the eps-floor gap invariant |d| <~ 55: no overflow).
#define RENORM4                                                               \
    {                                                                         \
        const int x = fexp_of(fmaxf(aE, aO));                                 \
        aE = fldexp(aE, -x); aO = fldexp(aO, -x); aZ = fldexp(aZ, -x);        \
        e += x;                                                               \
    }

// d = e(i-1) - e(i), valid for the next 4-step window (e frozen, no dead
// lanes in phase B). Lane 0: -16384 -> fldexp underflows to exact 0.
#define DCALC                                                                 \
    {                                                                         \
        const int ep = ror1_i(e);                                             \
        d = isL0 ? (-16384) : (ep - e);                                       \
    }

#define RENORM4B { RENORM4 DCALC }

// ---- phase-B lean step (all lanes live; d frozen per window) ----
#define BLSTEP(pL, pB)                                                        \
    {                                                                         \
        const float pBe = (pB) + EPS_;                                        \
        const float pLe = (pL) + EPS_;                                        \
        const float prevO = fldexp(ror1_f(aO), d);                            \
        const float nE = (aE + prevO) * pBe;                                  \
        const float nO = __builtin_fmaf(skf, prevO, aO + aE) * pLe;           \
        aZ = (aZ + aO) * pBe;                                                 \
        aE = nE; aO = nO;                                                     \
    }

#define ACHUNK(RL, RB)                                                        \
    {                                                                         \
        _Pragma("unroll")                                                     \
        for (int k = 0; k < 32; ++k) {                                        \
            ALSTEP(RL[k], RB[k])                                              \
            if ((k & 3) == 3) RENORM4                                         \
        }                                                                     \
    }

#define BCHUNK32(RL, RB)                                                      \
    {                                                                         \
        _Pragma("unroll")                                                     \
        for (int k = 0; k < 32; ++k) {                                        \
            BLSTEP(RL[k], RB[k])                                              \
            if ((k & 3) == 3) RENORM4B                                        \
        }                                                                     \
    }

// Stage chunk k (rows t = 1+32k .. 32+32k; k==31 -> final 31 rows).
#define STAGE_CHUNK(k, LOFF)                                                  \
    {                                                                         \
        const float* src = base + (size_t)(1 + 32 * (k)) * C_;                \
        const int nKB = ((k) == 31) ? 15 : 16;                                \
        _Pragma("unroll")                                                     \
        for (int j = 0; j < 16; ++j)                                          \
            if (j < nKB)                                                      \
                g2l16(src + j * 256 + lane * 4, sm + (LOFF) + j * 256);       \
        if ((k) == 31) {                                                      \
            const float* s2 = src + 15 * 256;                                 \
            g2l4(s2 + lane,      sm + (LOFF) + 15 * 256);                     \
            g2l4(s2 + 64 + lane, sm + (LOFF) + 15 * 256 + 64);                \
        }                                                                     \
    }

#define BURST(LOFF, RL, RB, NR)                                               \
    {                                                                         \
        _Pragma("unroll")                                                     \
        for (int j = 0; j < (NR); ++j) {                                      \
            RL[j] = sm[(LOFF) + j * C_ + lab];                                \
            RB[j] = sm[(LOFF) + j * C_ + BLANK_];                             \
        }                                                                     \
    }

#define VMWAIT asm volatile("s_waitcnt vmcnt(0)" ::: "memory")

__global__ __launch_bounds__(64, 1)
void ctc_fwd(const int* __restrict__ yt, const float* __restrict__ yp,
             float* __restrict__ out) {
    __shared__ float sm[3 * LDSF];                // 48 KB, 3-slot rotation

    const int b    = blockIdx.x;
    const int lane = threadIdx.x;                 // 0..63
    const int lab  = yt[b * L_ + lane];           // label of state 2*lane+1
    const int labp = __shfl_up(lab, 1);           // init-only
    const bool can_skip = (lane > 0) && (lab != labp);
    const bool isL0     = (lane == 0);
    const float skf     = can_skip ? 1.0f : 0.0f;

    const float* __restrict__ base = yp + (size_t)b * T_ * C_;

    // ---- prologue: stage chunks 0 and 1 ----
    STAGE_CHUNK(0, 0)
    STAGE_CHUNK(1, LDSF)

    // ---- t=0 init: state 0 = lane0.aE, state 1 = lane0.aO ----
    float aE = isL0 ? (base[BLANK_] + EPS_) : 0.0f;
    float aO = isL0 ? (base[lab]    + EPS_) : 0.0f;
    float aZ = 0.0f;                              // state 128 (lane 63)
    int   e  = 0, d = 0;

    VMWAIT;                                       // slots 0,1 + init loads

    float rl0[32], rb0[32], rl1[32], rb1[32];
    BURST(0, rl0, rb0, 32)                        // chunk 0

    // ---- phase A: chunks 0..3 (t = 1..128), per-step adoption ----
    STAGE_CHUNK(2, 2 * LDSF)
    BURST(LDSF, rl1, rb1, 32)                     // chunk 1
    ACHUNK(rl0, rb0)                              // t 1..32
    VMWAIT;

    STAGE_CHUNK(3, 0)
    BURST(2 * LDSF, rl0, rb0, 32)                 // chunk 2
    ACHUNK(rl1, rb1)                              // t 33..64
    VMWAIT;

    STAGE_CHUNK(4, LDSF)
    BURST(0, rl1, rb1, 32)                        // chunk 3
    ACHUNK(rl0, rb0)                              // t 65..96
    VMWAIT;

    STAGE_CHUNK(5, 2 * LDSF)
    BURST(LDSF, rl0, rb0, 32)                     // chunk 4
    ACHUNK(rl1, rb1)                              // t 97..128
    VMWAIT;

    DCALC                                         // first phase-B window

    // ---- phase B: chunks 4..29 in pairs (t = 129..960) ----
#pragma unroll 1
    for (int c = 4; c <= 28; c += 2) {
        {   // compute chunk c (regs 0); burst c+1; stage c+2
            STAGE_CHUNK(c + 2, ((c + 2) % 3) * LDSF)
            BURST(((c + 1) % 3) * LDSF, rl1, rb1, 32)
            BCHUNK32(rl0, rb0)
            VMWAIT;
        }
        {   // compute chunk c+1 (regs 1); burst c+2; stage c+3
            STAGE_CHUNK(c + 3, ((c + 3) % 3) * LDSF)
            BURST(((c + 2) % 3) * LDSF, rl0, rb0, 32)
            BCHUNK32(rl1, rb1)
            VMWAIT;
        }
    }

    // ---- chunk 30 (t = 961..992); burst chunk 31 (31 rows, slot 31%3) ----
    BURST((31 % 3) * LDSF, rl1, rb1, 31)
    BCHUNK32(rl0, rb0)

    // ---- chunk 31: t = 993..1023 (31 steps) ----
#pragma unroll
    for (int k = 0; k < 31; ++k) {
        BLSTEP(rl1[k], rb1[k])
        if ((k & 3) == 3) RENORM4B
    }

    // loss = -ln(alpha[127] + alpha[128]); aO,aZ share lane-63 scale 2^e.
    if (lane == 63) {
        const float s = aO + aZ;
        out[b] = -(flog2(s) + (float)e) * LN2_;
    }
}

extern "C" void kernel_launch(void* const* d_in, const int* in_sizes, int n_in,
                              void* d_out, int out_size, void* d_ws, size_t ws_size,
                              hipStream_t stream) {
    const int*   y_true = (const int*)d_in[0];
    const float* y_pred = (const float*)d_in[1];
    float*       out    = (float*)d_out;
    ctc_fwd<<<B_, 64, 0, stream>>>(y_true, y_pred, out);
}